// Round 9
// baseline (215.685 us; speedup 1.0000x reference)
//
#include <hip/hip_runtime.h>
#include <hip/hip_bf16.h>
#include <cstddef>
#include <cstdint>

#define S_LEN  2048
#define DMODEL 1024
#define NHEADS 16

typedef __attribute__((ext_vector_type(8))) short  short8;
typedef __attribute__((ext_vector_type(4))) short  s16x4;   // 'short4' is taken by HIP
typedef __attribute__((ext_vector_type(8))) __bf16 bf16x8;
typedef __attribute__((ext_vector_type(4))) float  f32x4;

__device__ __forceinline__ f32x4 MFMA(short8 a, short8 b, f32x4 c) {
    return __builtin_amdgcn_mfma_f32_16x16x32_bf16(
        __builtin_bit_cast(bf16x8, a), __builtin_bit_cast(bf16x8, b), c, 0, 0, 0);
}

__device__ __forceinline__ unsigned short f2bs(float f) {
    return __builtin_bit_cast(unsigned short, __float2bfloat16(f));
}
__device__ __forceinline__ float bs2f(unsigned short u) {
    unsigned int x = ((unsigned int)u) << 16;
    return __builtin_bit_cast(float, x);
}

__device__ __forceinline__ short8 cvt8(f32x4 a, f32x4 b) {
    short8 r;
#pragma unroll
    for (int i = 0; i < 4; ++i) {
        r[i]     = (short)f2bs(a[i]);
        r[4 + i] = (short)f2bs(b[i]);
    }
    return r;
}

// scale a bf16x8 by 0.125f (exact: power-of-two exponent shift)
__device__ __forceinline__ short8 scale8(short8 v) {
    short8 r;
#pragma unroll
    for (int i = 0; i < 8; ++i)
        r[i] = (short)f2bs(bs2f((unsigned short)v[i]) * 0.125f);
    return r;
}

// T1: XCD-bijective block remap (requires nwg % 8 == 0)
__device__ __forceinline__ int xcd_swz(int bid, int nwg) {
    const int chunk = nwg >> 3;
    return (bid & 7) * chunk + (bid >> 3);
}

// ---------------------------------------------------------------------------
// GEMM: C[M,N] = A[M,K] * W[N,K]^T + bias[N], K = DMODEL = 1024.
// 128x128 tile, BK=32, 256 threads (4 waves, 2x2), mfma 16x16x32 bf16.
//  - A: double-buffered LDS (reg-staged, XOR-swizzled 16B slots).
//  - W: NO LDS — per-wave fragments load global->reg directly (L2-resident
//    panel), prefetched one K-step ahead into alternating named reg sets.
//  - One barrier per K-step; W path is barrier-free.
// ---------------------------------------------------------------------------
template<bool HEADSPLIT>
__device__ __forceinline__ void gemm_body(const void* __restrict__ Ap,
                                          const float* __restrict__ W,
                                          const float* __restrict__ bias,
                                          void* __restrict__ outp,
                                          int m0, int n0)
{
    __shared__ short a_lds[2][128 * 32];
    const int t    = threadIdx.x;
    const int lane = t & 63;
    const int wid  = t >> 6;
    const int wr   = (wid >> 1) << 6;   // wave row offset: 0 / 64
    const int wc   = (wid & 1) << 6;    // wave col offset: 0 / 64
    const int fr   = lane & 15;
    const int ks   = lane >> 4;         // 16B k-slot 0..3

    const int row0 = t >> 2,         sl0 = t & 3;
    const int row1 = (256 + t) >> 2, sl1 = (256 + t) & 3;
    const int ms0  = sl0 ^ ((row0 >> 1) & 3);
    const int ms1  = sl1 ^ ((row1 >> 1) & 3);

    short8 av_b[2];        // A staging when bf16
    f32x4  av_f[2][2];     // A staging when f32

    auto load_A = [&](int k0) {
        if constexpr (HEADSPLIT) {
            const float* A = (const float*)Ap;
            const float* pa0 = A + (size_t)(m0 + row0) * DMODEL + k0 + sl0 * 8;
            av_f[0][0] = ((const f32x4*)pa0)[0]; av_f[0][1] = ((const f32x4*)pa0)[1];
            const float* pa1 = A + (size_t)(m0 + row1) * DMODEL + k0 + sl1 * 8;
            av_f[1][0] = ((const f32x4*)pa1)[0]; av_f[1][1] = ((const f32x4*)pa1)[1];
        } else {
            const unsigned short* A = (const unsigned short*)Ap;
            av_b[0] = *(const short8*)(A + (size_t)(m0 + row0) * DMODEL + k0 + sl0 * 8);
            av_b[1] = *(const short8*)(A + (size_t)(m0 + row1) * DMODEL + k0 + sl1 * 8);
        }
    };
    auto store_A = [&](int buf) {
        if constexpr (HEADSPLIT) {
            *(short8*)&a_lds[buf][row0 * 32 + ms0 * 8] = cvt8(av_f[0][0], av_f[0][1]);
            *(short8*)&a_lds[buf][row1 * 32 + ms1 * 8] = cvt8(av_f[1][0], av_f[1][1]);
        } else {
            *(short8*)&a_lds[buf][row0 * 32 + ms0 * 8] = av_b[0];
            *(short8*)&a_lds[buf][row1 * 32 + ms1 * 8] = av_b[1];
        }
    };

    // W fragment base: lane (fr,ks) reads row n0+wc+ni*16+fr, cols k0+ks*8..
    const float* wbase = W + (size_t)(n0 + wc + fr) * DMODEL + ks * 8;
    auto load_W = [&](int k0, f32x4 (&wf)[4][2]) {
#pragma unroll
        for (int ni = 0; ni < 4; ++ni) {
            const float* p = wbase + (size_t)(ni * 16) * DMODEL + k0;
            wf[ni][0] = ((const f32x4*)p)[0];
            wf[ni][1] = ((const f32x4*)p)[1];
        }
    };

    // prologue: A tile 0 -> buf 0; A tile 1 + W step 0 in flight
    load_A(0);
    store_A(0);
    load_A(32);
    f32x4 wfA[4][2], wfB[4][2];
    load_W(0, wfA);
    __syncthreads();

    f32x4 acc[4][4] = {};

    auto step = [&](int kidx, const f32x4 (&wcur)[4][2], f32x4 (&wnxt)[4][2]) {
        const int cur = kidx & 1;
        short8 af[4], bfr[4];
#pragma unroll
        for (int i = 0; i < 4; ++i) {
            const int ra = wr + i * 16 + fr;
            af[i] = *(const short8*)&a_lds[cur][ra * 32 + ((ks ^ ((ra >> 1) & 3)) << 3)];
        }
#pragma unroll
        for (int ni = 0; ni < 4; ++ni) bfr[ni] = cvt8(wcur[ni][0], wcur[ni][1]);
        if (kidx + 1 < 32) load_W((kidx + 1) * 32, wnxt);   // W prefetch (reg)
#pragma unroll
        for (int mi = 0; mi < 4; ++mi)
#pragma unroll
            for (int ni = 0; ni < 4; ++ni)
                acc[mi][ni] = MFMA(af[mi], bfr[ni], acc[mi][ni]);
        if (kidx + 1 < 32) {
            store_A(cur ^ 1);                      // A tile kidx+1 (vmcnt here)
            if (kidx + 2 < 32) load_A((kidx + 2) * 32);
        }
        __syncthreads();
    };

    for (int k2 = 0; k2 < 32; k2 += 2) {   // hand 2-step rotation (rule #20)
        step(k2,     wfA, wfB);
        step(k2 + 1, wfB, wfA);
    }

#pragma unroll
    for (int ni = 0; ni < 4; ++ni) {
        const int n    = n0 + wc + ni * 16 + fr;   // D col = lane&15
        const float bv = bias[n];
#pragma unroll
        for (int mi = 0; mi < 4; ++mi) {
#pragma unroll
            for (int j = 0; j < 4; ++j) {
                const int m = m0 + wr + mi * 16 + ks * 4 + j;  // D row = (lane>>4)*4+j
                const float val = acc[mi][ni][j] + bv;
                if constexpr (HEADSPLIT) {
                    const int b = m >> 11, s = m & (S_LEN - 1);
                    const int hh = n >> 6, dh = n & 63;
                    ((unsigned short*)outp)[((((size_t)b * NHEADS + hh) * S_LEN + s) << 6) + dh]
                        = f2bs(val);
                } else {
                    ((float*)outp)[(size_t)m * DMODEL + n] = val;
                }
            }
        }
    }
}

__global__ __launch_bounds__(256, 3)
void qkv_gemm(const float* __restrict__ Q, const float* __restrict__ K,
              const float* __restrict__ V,
              const float* __restrict__ Wq, const float* __restrict__ Wk,
              const float* __restrict__ Wv,
              const float* __restrict__ bq, const float* __restrict__ bk,
              const float* __restrict__ bv,
              unsigned short* qh, unsigned short* kh, unsigned short* vh)
{
    const int swz = xcd_swz(blockIdx.x, 768);   // 3 x 32 x 8 blocks
    const int z   = swz >> 8;
    const int rem = swz & 255;
    const int my  = rem >> 3;                   // M-tile (32)
    const int nx  = rem & 7;                    // N-tile (8)
    const float *A, *W, *B; unsigned short* O;
    if (z == 0)      { A = Q; W = Wq; B = bq; O = qh; }
    else if (z == 1) { A = K; W = Wk; B = bk; O = kh; }
    else             { A = V; W = Wv; B = bv; O = vh; }
    gemm_body<true>(A, W, B, O, my * 128, nx * 128);
}

__global__ __launch_bounds__(256, 3)
void out_gemm(const unsigned short* __restrict__ X, const float* __restrict__ Wo,
              const float* __restrict__ bo, float* __restrict__ out)
{
    const int swz = xcd_swz(blockIdx.x, 256);   // 32 x 8 blocks
    gemm_body<false>(X, Wo, bo, out, (swz >> 3) * 128, (swz & 7) * 128);
}

// ---------------------------------------------------------------------------
// Flash attention, causal, swapped-operand layout, CAUSAL-PAIRED q-tiles.
// Block = (b,h) x q-tiles {x, 31-x} sharing one K/V staging loop; 4 waves x
// 16 q-rows per q-tile. T14 prefetch, T13 defer-max, T5 setprio, T1 swizzle.
// ---------------------------------------------------------------------------
#define VSTR 72
#define PSTR 88

struct QState {
    short8 qf0, qf1;   // scaled Q fragments (B operand)
    f32x4  oacc[4];    // O^T: oacc[nd][jj] = O[q=myq][dh=nd*16+ks*4+jj]
    float  m, l;
    int    qr0;        // wave's first q row for this q-tile
};

__device__ __forceinline__ void attn_tile(QState& st, const int k0,
                                          const short* k_lds, const short* v_lds,
                                          short* p_buf, const int fr, const int ks)
{
    const int myq = st.qr0 + fr;
    // ---- QK^T (swapped): sacc[nk][jj] = S^T[key=k0+nk*16+ks*4+jj][q=myq]
    f32x4 sacc[4] = {};
    __builtin_amdgcn_s_setprio(1);
#pragma unroll
    for (int nk = 0; nk < 4; ++nk) {
        const int rb = nk * 16 + fr;         // key row (A operand row)
        short8 a0 = *(const short8*)&k_lds[rb * 64 + (((ks)     ^ (rb & 7)) << 3)];
        short8 a1 = *(const short8*)&k_lds[rb * 64 + (((4 + ks) ^ (rb & 7)) << 3)];
        sacc[nk] = MFMA(a0, st.qf0, sacc[nk]);
        sacc[nk] = MFMA(a1, st.qf1, sacc[nk]);
    }
    __builtin_amdgcn_s_setprio(0);

    // ---- online softmax (scale folded into Q) ----
    float mx = -1e9f;
    if (k0 + 63 <= st.qr0) {             // wave-uniform: no masking needed
#pragma unroll
        for (int nk = 0; nk < 4; ++nk)
#pragma unroll
            for (int jj = 0; jj < 4; ++jj) mx = fmaxf(mx, sacc[nk][jj]);
    } else {
#pragma unroll
        for (int nk = 0; nk < 4; ++nk)
#pragma unroll
            for (int jj = 0; jj < 4; ++jj) {
                const int key = k0 + nk * 16 + ks * 4 + jj;
                float s = (key <= myq) ? sacc[nk][jj] : -1e9f;
                sacc[nk][jj] = s;
                mx = fmaxf(mx, s);
            }
    }
    mx = fmaxf(mx, __shfl_xor(mx, 16));
    mx = fmaxf(mx, __shfl_xor(mx, 32));
    if (!__all(mx <= st.m + 8.f)) {      // T13 defer-max
        const float mnew = fmaxf(st.m, mx);
        const float corr = __expf(st.m - mnew);
        st.m = mnew;
        st.l *= corr;
#pragma unroll
        for (int nd = 0; nd < 4; ++nd)
#pragma unroll
            for (int jj = 0; jj < 4; ++jj) st.oacc[nd][jj] *= corr;
    }

    float rsum = 0.f;
#pragma unroll
    for (int nk = 0; nk < 4; ++nk) {
        s16x4 pw;
#pragma unroll
        for (int jj = 0; jj < 4; ++jj) {
            const float p = __expf(sacc[nk][jj] - st.m);
            rsum += p;
            pw[jj] = (short)f2bs(p);
        }
        *(s16x4*)&p_buf[fr * PSTR + nk * 16 + ks * 4] = pw;
    }
    rsum += __shfl_xor(rsum, 16);
    rsum += __shfl_xor(rsum, 32);
    st.l += rsum;
    asm volatile("" ::: "memory");       // order P writes before P reads

    // ---- PV (swapped): O^T += V^T * P^T ----
    __builtin_amdgcn_s_setprio(1);
#pragma unroll
    for (int sh = 0; sh < 2; ++sh) {
        short8 pa = *(const short8*)&p_buf[fr * PSTR + sh * 32 + ks * 8];
#pragma unroll
        for (int nd = 0; nd < 4; ++nd) {
            short8 vf = *(const short8*)&v_lds[(nd * 16 + fr) * VSTR + sh * 32 + ks * 8];
            st.oacc[nd] = MFMA(vf, pa, st.oacc[nd]);
        }
    }
    __builtin_amdgcn_s_setprio(0);
}

__global__ __launch_bounds__(256, 2)
void attn_kernel(const unsigned short* __restrict__ qh,
                 const unsigned short* __restrict__ kh,
                 const unsigned short* __restrict__ vh,
                 unsigned short* __restrict__ xh)
{
    __shared__ short k_lds[64 * 64];
    __shared__ short v_lds[64 * VSTR];
    __shared__ short p_lds[4][16 * PSTR];

    const int t    = threadIdx.x;
    const int lane = t & 63;
    const int wid  = t >> 6;
    const int fr   = lane & 15;
    const int ks   = lane >> 4;
    const int swz  = xcd_swz(blockIdx.x, 512);   // 32 bh x 16 pairs
    const int bh   = swz >> 4;            // b*16 + h  (contiguous per XCD)
    const int xp   = swz & 15;            // paired q-tiles: xp and 31-xp
    const int qa0  = xp * 64;
    const int qb0  = (31 - xp) * 64;
    const int ntA  = xp + 1;              // K-tiles for qa
    const int ntB  = 32 - xp;             // K-tiles for qb (>= ntA+1)

    const unsigned short* qb_ = qh + ((size_t)bh << 17);   // *S_LEN*64
    const unsigned short* kb  = kh + ((size_t)bh << 17);
    const unsigned short* vb  = vh + ((size_t)bh << 17);

    QState A, B;
    A.qr0 = qa0 + wid * 16;  B.qr0 = qb0 + wid * 16;
    A.qf0 = scale8(*(const short8*)&qb_[(A.qr0 + fr) * 64 + ks * 8]);
    A.qf1 = scale8(*(const short8*)&qb_[(A.qr0 + fr) * 64 + 32 + ks * 8]);
    B.qf0 = scale8(*(const short8*)&qb_[(B.qr0 + fr) * 64 + ks * 8]);
    B.qf1 = scale8(*(const short8*)&qb_[(B.qr0 + fr) * 64 + 32 + ks * 8]);
#pragma unroll
    for (int nd = 0; nd < 4; ++nd) { A.oacc[nd] = f32x4{}; B.oacc[nd] = f32x4{}; }
    A.m = B.m = -1e9f; A.l = B.l = 0.f;

    // prologue: load tile 0 into registers
    short8 kv[2], vv[2];
#pragma unroll
    for (int cc = 0; cc < 2; ++cc) {
        const int c   = cc * 256 + t;
        const int row = c >> 3;
        const int sl  = c & 7;
        kv[cc] = *(const short8*)(kb + (size_t)row * 64 + sl * 8);
        const int key = c & 63;
        const int d0  = (c >> 6) * 8;
        vv[cc] = *(const short8*)(vb + (size_t)key * 64 + d0);
    }

    for (int kt = 0; kt < ntB; ++kt) {
        const int k0 = kt * 64;
        __syncthreads();                  // previous tile fully consumed

#pragma unroll
        for (int cc = 0; cc < 2; ++cc) {
            const int c   = cc * 256 + t;
            const int row = c >> 3;
            const int ms  = (c & 7) ^ (row & 7);
            *(short8*)&k_lds[row * 64 + ms * 8] = kv[cc];
            const int key = c & 63;
            const int d0  = (c >> 6) * 8;
#pragma unroll
            for (int i = 0; i < 8; ++i)
                v_lds[(d0 + i) * VSTR + key] = vv[cc][i];
        }
        __syncthreads();

        // T14 prefetch: issue next tile's global loads before compute
        if (kt + 1 < ntB) {
            const int k1 = k0 + 64;
#pragma unroll
            for (int cc = 0; cc < 2; ++cc) {
                const int c   = cc * 256 + t;
                const int row = c >> 3;
                const int sl  = c & 7;
                kv[cc] = *(const short8*)(kb + (size_t)(k1 + row) * 64 + sl * 8);
                const int key = c & 63;
                const int d0  = (c >> 6) * 8;
                vv[cc] = *(const short8*)(vb + (size_t)(k1 + key) * 64 + d0);
            }
        }

        attn_tile(B, k0, k_lds, v_lds, p_lds[wid], fr, ks);
        if (kt < ntA)
            attn_tile(A, k0, k_lds, v_lds, p_lds[wid], fr, ks);
    }

    // ---- finalize both q-tiles ----
    const int b = bh >> 4, h = bh & 15;
#pragma unroll
    for (int which = 0; which < 2; ++which) {
        QState& st = which ? B : A;
        const float inv = 1.f / st.l;
        const size_t base = ((size_t)b * S_LEN + (st.qr0 + fr)) * DMODEL + h * 64;
#pragma unroll
        for (int nd = 0; nd < 4; ++nd)
#pragma unroll
            for (int jj = 0; jj < 4; ++jj)
                xh[base + nd * 16 + ks * 4 + jj] = f2bs(st.oacc[nd][jj] * inv);
    }
}

// ---------------------------------------------------------------------------
extern "C" void kernel_launch(void* const* d_in, const int* in_sizes, int n_in,
                              void* d_out, int out_size, void* d_ws, size_t ws_size,
                              hipStream_t stream)
{
    const float* Q  = (const float*)d_in[0];
    const float* K  = (const float*)d_in[1];
    const float* V  = (const float*)d_in[2];
    // d_in[3] = attn_mask (causal triu k=1, hardcoded), d_in[4] = padding (none)
    const float* Wq = (const float*)d_in[5];
    const float* bq = (const float*)d_in[6];
    const float* Wk = (const float*)d_in[7];
    const float* bk = (const float*)d_in[8];
    const float* Wv = (const float*)d_in[9];
    const float* bv = (const float*)d_in[10];
    const float* Wo = (const float*)d_in[11];
    const float* bo = (const float*)d_in[12];
    float* out = (float*)d_out;

    const size_t HSZ = (size_t)2 * S_LEN * DMODEL;   // 4,194,304 elems
    unsigned short* qh = (unsigned short*)d_ws;       // bf16 workspace
    unsigned short* kh = qh + HSZ;
    unsigned short* vh = kh + HSZ;
    unsigned short* xh = vh + HSZ;                    // 33.6 MB total in d_ws

    qkv_gemm<<<768, 256, 0, stream>>>(Q, K, V, Wq, Wk, Wv, bq, bk, bv, qh, kh, vh);
    attn_kernel<<<512, 256, 0, stream>>>(qh, kh, vh, xh);
    out_gemm<<<256, 256, 0, stream>>>(xh, Wo, bo, out);
}

// Round 10
// 108.968 us; speedup vs baseline: 1.9793x; 1.9793x over previous
//
#include <hip/hip_runtime.h>
#include <hip/hip_bf16.h>
#include <cstddef>
#include <cstdint>

#define S_LEN  2048
#define DMODEL 1024
#define NHEADS 16

typedef __attribute__((ext_vector_type(8))) short  short8;
typedef __attribute__((ext_vector_type(4))) short  s16x4;   // 'short4' is taken by HIP
typedef __attribute__((ext_vector_type(8))) __bf16 bf16x8;
typedef __attribute__((ext_vector_type(4))) float  f32x4;

__device__ __forceinline__ f32x4 MFMA(short8 a, short8 b, f32x4 c) {
    return __builtin_amdgcn_mfma_f32_16x16x32_bf16(
        __builtin_bit_cast(bf16x8, a), __builtin_bit_cast(bf16x8, b), c, 0, 0, 0);
}

__device__ __forceinline__ unsigned short f2bs(float f) {
    return __builtin_bit_cast(unsigned short, __float2bfloat16(f));
}
__device__ __forceinline__ float bs2f(unsigned short u) {
    unsigned int x = ((unsigned int)u) << 16;
    return __builtin_bit_cast(float, x);
}

__device__ __forceinline__ short8 cvt8(f32x4 a, f32x4 b) {
    short8 r;
#pragma unroll
    for (int i = 0; i < 4; ++i) {
        r[i]     = (short)f2bs(a[i]);
        r[4 + i] = (short)f2bs(b[i]);
    }
    return r;
}

// scale a bf16x8 by 0.125f (exact: power-of-two exponent shift)
__device__ __forceinline__ short8 scale8(short8 v) {
    short8 r;
#pragma unroll
    for (int i = 0; i < 8; ++i)
        r[i] = (short)f2bs(bs2f((unsigned short)v[i]) * 0.125f);
    return r;
}

// T1: XCD-bijective block remap (requires nwg % 8 == 0)
__device__ __forceinline__ int xcd_swz(int bid, int nwg) {
    const int chunk = nwg >> 3;
    return (bid & 7) * chunk + (bid >> 3);
}

// T4: barrier that does NOT drain vmcnt — LDS ops flushed, global loads
// stay in flight across it (raw s_barrier; __syncthreads would emit
// s_waitcnt vmcnt(0) and kill the prefetch).
__device__ __forceinline__ void bar_sync() {
    asm volatile("s_waitcnt lgkmcnt(0)" ::: "memory");
    __builtin_amdgcn_sched_barrier(0);
    __builtin_amdgcn_s_barrier();
}

// ---------------------------------------------------------------------------
// GEMM: C[M,N] = A[M,K] * W[N,K]^T + bias[N], K = DMODEL = 1024.
// 128x128 tile, BK=32, 256 threads (4 waves, 2x2), mfma 16x16x32 bf16.
// DOUBLE-BUFFERED LDS, one raw barrier per K-step; loads for tile t+2 are
// issued before the barrier and span it (counted vmcnt by data-dep only).
// LDS image: [row][32] bf16, 16B slots XOR-swizzled by ((row>>1)&3).
// ---------------------------------------------------------------------------
template<bool HEADSPLIT>
__device__ __forceinline__ void gemm_body(const void* __restrict__ Ap,
                                          const float* __restrict__ W,
                                          const float* __restrict__ bias,
                                          void* __restrict__ outp,
                                          int m0, int n0)
{
    __shared__ short a_lds[2][128 * 32];
    __shared__ short w_lds[2][128 * 32];
    const int t    = threadIdx.x;
    const int lane = t & 63;
    const int wid  = t >> 6;
    const int wr   = (wid >> 1) << 6;   // wave row offset: 0 / 64
    const int wc   = (wid & 1) << 6;    // wave col offset: 0 / 64
    const int fr   = lane & 15;
    const int ks   = lane >> 4;         // 16B k-slot 0..3

    const int row0 = t >> 2,         sl0 = t & 3;
    const int row1 = (256 + t) >> 2, sl1 = (256 + t) & 3;
    const int ms0  = sl0 ^ ((row0 >> 1) & 3);
    const int ms1  = sl1 ^ ((row1 >> 1) & 3);

    short8 av_b[2];        // A staging when bf16
    f32x4  av_f[2][2];     // A staging when f32
    f32x4  wv_f[2][2];     // W staging (always f32)

    auto load_tile = [&](int k0) {
        if constexpr (HEADSPLIT) {
            const float* A = (const float*)Ap;
            const float* pa0 = A + (size_t)(m0 + row0) * DMODEL + k0 + sl0 * 8;
            av_f[0][0] = ((const f32x4*)pa0)[0]; av_f[0][1] = ((const f32x4*)pa0)[1];
            const float* pa1 = A + (size_t)(m0 + row1) * DMODEL + k0 + sl1 * 8;
            av_f[1][0] = ((const f32x4*)pa1)[0]; av_f[1][1] = ((const f32x4*)pa1)[1];
        } else {
            const unsigned short* A = (const unsigned short*)Ap;
            av_b[0] = *(const short8*)(A + (size_t)(m0 + row0) * DMODEL + k0 + sl0 * 8);
            av_b[1] = *(const short8*)(A + (size_t)(m0 + row1) * DMODEL + k0 + sl1 * 8);
        }
        const float* pw0 = W + (size_t)(n0 + row0) * DMODEL + k0 + sl0 * 8;
        wv_f[0][0] = ((const f32x4*)pw0)[0]; wv_f[0][1] = ((const f32x4*)pw0)[1];
        const float* pw1 = W + (size_t)(n0 + row1) * DMODEL + k0 + sl1 * 8;
        wv_f[1][0] = ((const f32x4*)pw1)[0]; wv_f[1][1] = ((const f32x4*)pw1)[1];
    };

    auto store_tile = [&](int buf) {
        if constexpr (HEADSPLIT) {
            *(short8*)&a_lds[buf][row0 * 32 + ms0 * 8] = cvt8(av_f[0][0], av_f[0][1]);
            *(short8*)&a_lds[buf][row1 * 32 + ms1 * 8] = cvt8(av_f[1][0], av_f[1][1]);
        } else {
            *(short8*)&a_lds[buf][row0 * 32 + ms0 * 8] = av_b[0];
            *(short8*)&a_lds[buf][row1 * 32 + ms1 * 8] = av_b[1];
        }
        *(short8*)&w_lds[buf][row0 * 32 + ms0 * 8] = cvt8(wv_f[0][0], wv_f[0][1]);
        *(short8*)&w_lds[buf][row1 * 32 + ms1 * 8] = cvt8(wv_f[1][0], wv_f[1][1]);
    };

    // prologue: tile 0 -> buf 0; tile 1 in flight across the barrier
    load_tile(0);
    store_tile(0);
    load_tile(32);
    bar_sync();

    f32x4 acc[4][4] = {};

    for (int kidx = 0; kidx < 32; ++kidx) {
        const int cur = kidx & 1;

        short8 af[4], bfr[4];
#pragma unroll
        for (int i = 0; i < 4; ++i) {
            const int ra = wr + i * 16 + fr;
            af[i]  = *(const short8*)&a_lds[cur][ra * 32 + ((ks ^ ((ra >> 1) & 3)) << 3)];
            const int rb = wc + i * 16 + fr;
            bfr[i] = *(const short8*)&w_lds[cur][rb * 32 + ((ks ^ ((rb >> 1) & 3)) << 3)];
        }
#pragma unroll
        for (int mi = 0; mi < 4; ++mi)
#pragma unroll
            for (int ni = 0; ni < 4; ++ni)
                acc[mi][ni] = MFMA(af[mi], bfr[ni], acc[mi][ni]);

        if (kidx + 1 < 32) {
            store_tile(cur ^ 1);             // waits (counted) on tile t+1 loads
            if (kidx + 2 < 32) load_tile((kidx + 2) * 32);   // spans the barrier
        }
        bar_sync();
    }

#pragma unroll
    for (int ni = 0; ni < 4; ++ni) {
        const int n    = n0 + wc + ni * 16 + fr;   // D col = lane&15
        const float bv = bias[n];
#pragma unroll
        for (int mi = 0; mi < 4; ++mi) {
#pragma unroll
            for (int j = 0; j < 4; ++j) {
                const int m = m0 + wr + mi * 16 + ks * 4 + j;  // D row = (lane>>4)*4+j
                const float val = acc[mi][ni][j] + bv;
                if constexpr (HEADSPLIT) {
                    const int b = m >> 11, s = m & (S_LEN - 1);
                    const int hh = n >> 6, dh = n & 63;
                    ((unsigned short*)outp)[((((size_t)b * NHEADS + hh) * S_LEN + s) << 6) + dh]
                        = f2bs(val);
                } else {
                    ((float*)outp)[(size_t)m * DMODEL + n] = val;
                }
            }
        }
    }
}

__global__ __launch_bounds__(256, 3)
void qkv_gemm(const float* __restrict__ Q, const float* __restrict__ K,
              const float* __restrict__ V,
              const float* __restrict__ Wq, const float* __restrict__ Wk,
              const float* __restrict__ Wv,
              const float* __restrict__ bq, const float* __restrict__ bk,
              const float* __restrict__ bv,
              unsigned short* qh, unsigned short* kh, unsigned short* vh)
{
    const int swz = xcd_swz(blockIdx.x, 768);   // 3 x 32 x 8 blocks
    const int z   = swz >> 8;
    const int rem = swz & 255;
    const int my  = rem >> 3;                   // M-tile (32)
    const int nx  = rem & 7;                    // N-tile (8)
    const float *A, *W, *B; unsigned short* O;
    if (z == 0)      { A = Q; W = Wq; B = bq; O = qh; }
    else if (z == 1) { A = K; W = Wk; B = bk; O = kh; }
    else             { A = V; W = Wv; B = bv; O = vh; }
    gemm_body<true>(A, W, B, O, my * 128, nx * 128);
}

__global__ __launch_bounds__(256, 3)
void out_gemm(const unsigned short* __restrict__ X, const float* __restrict__ Wo,
              const float* __restrict__ bo, float* __restrict__ out)
{
    const int swz = xcd_swz(blockIdx.x, 256);   // 32 x 8 blocks
    gemm_body<false>(X, Wo, bo, out, (swz >> 3) * 128, (swz & 7) * 128);
}

// ---------------------------------------------------------------------------
// Flash attention, causal, swapped-operand layout, CAUSAL-PAIRED q-tiles.
// Block = (b,h) x q-tiles {x, 31-x} sharing one K/V staging loop; 4 waves x
// 16 q-rows per q-tile. T14 prefetch (now truly spanning the raw barriers),
// T13 defer-max, T5 setprio (attn only), T1 swizzle.
// ---------------------------------------------------------------------------
#define VSTR 72
#define PSTR 88

struct QState {
    short8 qf0, qf1;   // scaled Q fragments (B operand)
    f32x4  oacc[4];    // O^T: oacc[nd][jj] = O[q=myq][dh=nd*16+ks*4+jj]
    float  m, l;
    int    qr0;        // wave's first q row for this q-tile
};

__device__ __forceinline__ void attn_tile(QState& st, const int k0,
                                          const short* k_lds, const short* v_lds,
                                          short* p_buf, const int fr, const int ks)
{
    const int myq = st.qr0 + fr;
    // ---- QK^T (swapped): sacc[nk][jj] = S^T[key=k0+nk*16+ks*4+jj][q=myq]
    f32x4 sacc[4] = {};
    __builtin_amdgcn_s_setprio(1);
#pragma unroll
    for (int nk = 0; nk < 4; ++nk) {
        const int rb = nk * 16 + fr;         // key row (A operand row)
        short8 a0 = *(const short8*)&k_lds[rb * 64 + (((ks)     ^ (rb & 7)) << 3)];
        short8 a1 = *(const short8*)&k_lds[rb * 64 + (((4 + ks) ^ (rb & 7)) << 3)];
        sacc[nk] = MFMA(a0, st.qf0, sacc[nk]);
        sacc[nk] = MFMA(a1, st.qf1, sacc[nk]);
    }
    __builtin_amdgcn_s_setprio(0);

    // ---- online softmax (scale folded into Q) ----
    float mx = -1e9f;
    if (k0 + 63 <= st.qr0) {             // wave-uniform: no masking needed
#pragma unroll
        for (int nk = 0; nk < 4; ++nk)
#pragma unroll
            for (int jj = 0; jj < 4; ++jj) mx = fmaxf(mx, sacc[nk][jj]);
    } else {
#pragma unroll
        for (int nk = 0; nk < 4; ++nk)
#pragma unroll
            for (int jj = 0; jj < 4; ++jj) {
                const int key = k0 + nk * 16 + ks * 4 + jj;
                float s = (key <= myq) ? sacc[nk][jj] : -1e9f;
                sacc[nk][jj] = s;
                mx = fmaxf(mx, s);
            }
    }
    mx = fmaxf(mx, __shfl_xor(mx, 16));
    mx = fmaxf(mx, __shfl_xor(mx, 32));
    if (!__all(mx <= st.m + 8.f)) {      // T13 defer-max
        const float mnew = fmaxf(st.m, mx);
        const float corr = __expf(st.m - mnew);
        st.m = mnew;
        st.l *= corr;
#pragma unroll
        for (int nd = 0; nd < 4; ++nd)
#pragma unroll
            for (int jj = 0; jj < 4; ++jj) st.oacc[nd][jj] *= corr;
    }

    float rsum = 0.f;
#pragma unroll
    for (int nk = 0; nk < 4; ++nk) {
        s16x4 pw;
#pragma unroll
        for (int jj = 0; jj < 4; ++jj) {
            const float p = __expf(sacc[nk][jj] - st.m);
            rsum += p;
            pw[jj] = (short)f2bs(p);
        }
        *(s16x4*)&p_buf[fr * PSTR + nk * 16 + ks * 4] = pw;
    }
    rsum += __shfl_xor(rsum, 16);
    rsum += __shfl_xor(rsum, 32);
    st.l += rsum;
    asm volatile("" ::: "memory");       // order P writes before P reads

    // ---- PV (swapped): O^T += V^T * P^T ----
    __builtin_amdgcn_s_setprio(1);
#pragma unroll
    for (int sh = 0; sh < 2; ++sh) {
        short8 pa = *(const short8*)&p_buf[fr * PSTR + sh * 32 + ks * 8];
#pragma unroll
        for (int nd = 0; nd < 4; ++nd) {
            short8 vf = *(const short8*)&v_lds[(nd * 16 + fr) * VSTR + sh * 32 + ks * 8];
            st.oacc[nd] = MFMA(vf, pa, st.oacc[nd]);
        }
    }
    __builtin_amdgcn_s_setprio(0);
}

__global__ __launch_bounds__(256, 2)
void attn_kernel(const unsigned short* __restrict__ qh,
                 const unsigned short* __restrict__ kh,
                 const unsigned short* __restrict__ vh,
                 unsigned short* __restrict__ xh)
{
    __shared__ short k_lds[64 * 64];
    __shared__ short v_lds[64 * VSTR];
    __shared__ short p_lds[4][16 * PSTR];

    const int t    = threadIdx.x;
    const int lane = t & 63;
    const int wid  = t >> 6;
    const int fr   = lane & 15;
    const int ks   = lane >> 4;
    const int swz  = xcd_swz(blockIdx.x, 512);   // 32 bh x 16 pairs
    const int bh   = swz >> 4;            // b*16 + h  (contiguous per XCD)
    const int xp   = swz & 15;            // paired q-tiles: xp and 31-xp
    const int qa0  = xp * 64;
    const int qb0  = (31 - xp) * 64;
    const int ntA  = xp + 1;              // K-tiles for qa
    const int ntB  = 32 - xp;             // K-tiles for qb (>= ntA+1)

    const unsigned short* qb_ = qh + ((size_t)bh << 17);   // *S_LEN*64
    const unsigned short* kb  = kh + ((size_t)bh << 17);
    const unsigned short* vb  = vh + ((size_t)bh << 17);

    QState A, B;
    A.qr0 = qa0 + wid * 16;  B.qr0 = qb0 + wid * 16;
    A.qf0 = scale8(*(const short8*)&qb_[(A.qr0 + fr) * 64 + ks * 8]);
    A.qf1 = scale8(*(const short8*)&qb_[(A.qr0 + fr) * 64 + 32 + ks * 8]);
    B.qf0 = scale8(*(const short8*)&qb_[(B.qr0 + fr) * 64 + ks * 8]);
    B.qf1 = scale8(*(const short8*)&qb_[(B.qr0 + fr) * 64 + 32 + ks * 8]);
#pragma unroll
    for (int nd = 0; nd < 4; ++nd) { A.oacc[nd] = f32x4{}; B.oacc[nd] = f32x4{}; }
    A.m = B.m = -1e9f; A.l = B.l = 0.f;

    // prologue: load tile 0 into registers
    short8 kv[2], vv[2];
#pragma unroll
    for (int cc = 0; cc < 2; ++cc) {
        const int c   = cc * 256 + t;
        const int row = c >> 3;
        const int sl  = c & 7;
        kv[cc] = *(const short8*)(kb + (size_t)row * 64 + sl * 8);
        const int key = c & 63;
        const int d0  = (c >> 6) * 8;
        vv[cc] = *(const short8*)(vb + (size_t)key * 64 + d0);
    }

    for (int kt = 0; kt < ntB; ++kt) {
        const int k0 = kt * 64;
        bar_sync();                       // previous tile fully consumed

#pragma unroll
        for (int cc = 0; cc < 2; ++cc) {
            const int c   = cc * 256 + t;
            const int row = c >> 3;
            const int ms  = (c & 7) ^ (row & 7);
            *(short8*)&k_lds[row * 64 + ms * 8] = kv[cc];
            const int key = c & 63;
            const int d0  = (c >> 6) * 8;
#pragma unroll
            for (int i = 0; i < 8; ++i)
                v_lds[(d0 + i) * VSTR + key] = vv[cc][i];
        }
        bar_sync();

        // T14 prefetch: issue next tile's loads; they span the whole compute
        if (kt + 1 < ntB) {
            const int k1 = k0 + 64;
#pragma unroll
            for (int cc = 0; cc < 2; ++cc) {
                const int c   = cc * 256 + t;
                const int row = c >> 3;
                const int sl  = c & 7;
                kv[cc] = *(const short8*)(kb + (size_t)(k1 + row) * 64 + sl * 8);
                const int key = c & 63;
                const int d0  = (c >> 6) * 8;
                vv[cc] = *(const short8*)(vb + (size_t)(k1 + key) * 64 + d0);
            }
        }

        attn_tile(B, k0, k_lds, v_lds, p_lds[wid], fr, ks);
        if (kt < ntA)
            attn_tile(A, k0, k_lds, v_lds, p_lds[wid], fr, ks);
    }

    // ---- finalize both q-tiles ----
    const int b = bh >> 4, h = bh & 15;
#pragma unroll
    for (int which = 0; which < 2; ++which) {
        QState& st = which ? B : A;
        const float inv = 1.f / st.l;
        const size_t base = ((size_t)b * S_LEN + (st.qr0 + fr)) * DMODEL + h * 64;
#pragma unroll
        for (int nd = 0; nd < 4; ++nd)
#pragma unroll
            for (int jj = 0; jj < 4; ++jj)
                xh[base + nd * 16 + ks * 4 + jj] = f2bs(st.oacc[nd][jj] * inv);
    }
}

// ---------------------------------------------------------------------------
extern "C" void kernel_launch(void* const* d_in, const int* in_sizes, int n_in,
                              void* d_out, int out_size, void* d_ws, size_t ws_size,
                              hipStream_t stream)
{
    const float* Q  = (const float*)d_in[0];
    const float* K  = (const float*)d_in[1];
    const float* V  = (const float*)d_in[2];
    // d_in[3] = attn_mask (causal triu k=1, hardcoded), d_in[4] = padding (none)
    const float* Wq = (const float*)d_in[5];
    const float* bq = (const float*)d_in[6];
    const float* Wk = (const float*)d_in[7];
    const float* bk = (const float*)d_in[8];
    const float* Wv = (const float*)d_in[9];
    const float* bv = (const float*)d_in[10];
    const float* Wo = (const float*)d_in[11];
    const float* bo = (const float*)d_in[12];
    float* out = (float*)d_out;

    const size_t HSZ = (size_t)2 * S_LEN * DMODEL;   // 4,194,304 elems
    unsigned short* qh = (unsigned short*)d_ws;       // bf16 workspace
    unsigned short* kh = qh + HSZ;
    unsigned short* vh = kh + HSZ;
    unsigned short* xh = vh + HSZ;                    // 33.6 MB total in d_ws

    qkv_gemm<<<768, 256, 0, stream>>>(Q, K, V, Wq, Wk, Wv, bq, bk, bv, qh, kh, vh);
    attn_kernel<<<512, 256, 0, stream>>>(qh, kh, vh, xh);
    out_gemm<<<256, 256, 0, stream>>>(xh, Wo, bo, out);
}